// Round 10
// baseline (4152.857 us; speedup 1.0000x reference)
//
#include <hip/hip_runtime.h>
#include <hip/hip_bf16.h>

#define GN 16384
#define GH 16
#define GK 16
#define GL 4
#define HPS 20            // padded h row: 16 features + sq + 3 pad (80 B)

#define RPB 32            // rows per knn block
#define CAP 160           // collect buffer capacity per row
#define BSTR 161          // buffer row stride
#define SSTR 264          // phase-A merge row stride (256 vals + pad)
#define INFF __builtin_inff()

#define EREL 2.44140625e-4f   // 2^-12  (analysis bound ~2^-16, 16x headroom)
#define EABS 4.8828125e-4f    // 2^-11

typedef __attribute__((ext_vector_type(8)))  short v8s;
typedef __attribute__((ext_vector_type(16))) float f32x16;

// workspace float-offsets
#define OFF_H     0
#define OFF_IDX   (5*GN*HPS)
#define OFF_FLAGS (OFF_IDX + GN*GK)
#define OFF_XF    (OFF_FLAGS + GN)
#define OFF_EMBW  (OFF_XF + GN*3)
#define OFF_EMBB  (OFF_EMBW + 3*GH)
#define OFF_W1    (OFF_EMBB + GH)
#define OFF_B1    (OFF_W1 + GL*2*GH*GH)
#define OFF_W2    (OFF_B1 + GL*GH)
#define OFF_B2    (OFF_W2 + GL*GH*GH)
#define OFF_OW    (OFF_B2 + GL*GH)
#define OFF_OB    (OFF_OW + GL*GH*3)
#define OFF_DFLAG (OFF_OB + 4)
#define OFF_HA    (OFF_DFLAG + 8)       // GN*16 bf16
#define OFF_HB    (OFF_HA + GN*8)
#define OFF_HS    (OFF_HB + GN*8)       // GN*2 bf16 sq-split
#define OFF_TAB   (OFF_HS + GN)
#define OFF_PBAD  (OFF_TAB + 1024)
#define OFF_SQM   (OFF_PBAD + 4)

// ---------------------------------------------------------------------------
__device__ __forceinline__ short f2bs(float x)
{
    __hip_bfloat16 t = __float2bfloat16(x);
    return *(short*)&t;
}
// exact -2x on bf16 bits (exponent bump + sign flip); +-0 stays 0.
__device__ __forceinline__ short neg2bf(unsigned short v)
{
    return (v & 0x7FFFu) ? (short)((v + 0x0080u) ^ 0x8000u) : (short)0;
}

// ---------------------------------------------------------------------------
__global__ void detect_kernel(const unsigned short* __restrict__ raw,
                              int* __restrict__ flag)
{
    if (threadIdx.x == 0 && blockIdx.x == 0) {
        int cnt = 0;
        for (int i = 0; i < 64; ++i) {
            unsigned int bits = ((unsigned int)raw[2*i]) << 16;
            float v = __uint_as_float(bits);
            float a = fabsf(v);
            if (a > 1e-4f && a < 50.f) ++cnt;
        }
        *flag = (cnt >= 32) ? 1 : 0;
    }
}

__global__ void convert_kernel(const void* __restrict__ src,
                               float* __restrict__ dst, int n,
                               const int* __restrict__ flag)
{
    int i = blockIdx.x * 256 + threadIdx.x;
    if (i >= n) return;
    if (*flag)
        dst[i] = __bfloat162float(((const __hip_bfloat16*)src)[i]);
    else
        dst[i] = ((const float*)src)[i];
}

// ---------------------------------------------------------------------------
__device__ __forceinline__ float distt(const float hi[16], float sqi,
                                       const float* __restrict__ hj)
{
    float4 A = *(const float4*)(hj + 0);
    float4 B = *(const float4*)(hj + 4);
    float4 C = *(const float4*)(hj + 8);
    float4 D = *(const float4*)(hj + 12);
    float sqj = hj[16];
    float d0 = hi[0]*A.x;
    float d1 = hi[1]*A.y;
    d0 = fmaf(hi[2],  A.z, d0);  d1 = fmaf(hi[3],  A.w, d1);
    d0 = fmaf(hi[4],  B.x, d0);  d1 = fmaf(hi[5],  B.y, d1);
    d0 = fmaf(hi[6],  B.z, d0);  d1 = fmaf(hi[7],  B.w, d1);
    d0 = fmaf(hi[8],  C.x, d0);  d1 = fmaf(hi[9],  C.y, d1);
    d0 = fmaf(hi[10], C.z, d0);  d1 = fmaf(hi[11], C.w, d1);
    d0 = fmaf(hi[12], D.x, d0);  d1 = fmaf(hi[13], D.y, d1);
    d0 = fmaf(hi[14], D.z, d0);  d1 = fmaf(hi[15], D.w, d1);
    return fmaf(-2.f, d0 + d1, sqi + sqj);
}

#define LOAD_HI(ptr)                                                        \
    float hi[16]; float sqi;                                                \
    {                                                                       \
        const float* _hr = (ptr);                                           \
        float4 A = *(const float4*)(_hr + 0);                               \
        float4 B = *(const float4*)(_hr + 4);                               \
        float4 C = *(const float4*)(_hr + 8);                               \
        float4 D = *(const float4*)(_hr + 12);                              \
        hi[0]=A.x; hi[1]=A.y; hi[2]=A.z; hi[3]=A.w;                         \
        hi[4]=B.x; hi[5]=B.y; hi[6]=B.z; hi[7]=B.w;                         \
        hi[8]=C.x; hi[9]=C.y; hi[10]=C.z; hi[11]=C.w;                       \
        hi[12]=D.x; hi[13]=D.y; hi[14]=D.z; hi[15]=D.w;                     \
        sqi = _hr[16];                                                      \
    }

// ---------------------------------------------------------------------------
__global__ __launch_bounds__(256) void embed_kernel(
    const float* __restrict__ xf, const float* __restrict__ W,
    const float* __restrict__ b, float* __restrict__ h0)
{
    int i = blockIdx.x * 256 + threadIdx.x;
    float x0 = xf[i*3+0], x1 = xf[i*3+1], x2 = xf[i*3+2];
    float* orow = h0 + i * HPS;
    float sq = 0.f;
#pragma unroll
    for (int c = 0; c < GH; ++c) {
        float t = b[c];
        t = fmaf(x0, W[0*GH+c], t);
        t = fmaf(x1, W[1*GH+c], t);
        t = fmaf(x2, W[2*GH+c], t);
        t = fmaxf(t, 0.f);
        orow[c] = t;
        sq = fmaf(t, t, sq);
    }
    orow[16] = sq;
}

// ---------------------------------------------------------------------------
__global__ __launch_bounds__(256) void bfsplit_kernel(
    const float* __restrict__ hp, unsigned short* __restrict__ ha,
    unsigned short* __restrict__ hb, unsigned short* __restrict__ hs)
{
    int i = blockIdx.x * 256 + threadIdx.x;     // over GN*16
    int row = i >> 4, f = i & 15;
    float x = hp[row*HPS + f];
    __hip_bfloat16 a = __float2bfloat16(x);
    float af = __bfloat162float(a);
    __hip_bfloat16 b = __float2bfloat16(x - af);
    ha[i] = *(unsigned short*)&a;
    hb[i] = *(unsigned short*)&b;
    if (f == 0) {
        float sq = hp[row*HPS + 16];
        __hip_bfloat16 sa = __float2bfloat16(sq);
        float saf = __bfloat162float(sa);
        __hip_bfloat16 sb = __float2bfloat16(sq - saf);
        hs[row*2 + 0] = *(unsigned short*)&sa;
        hs[row*2 + 1] = *(unsigned short*)&sb;
    }
}

__global__ __launch_bounds__(1024) void sqmax_kernel(
    const float* __restrict__ hp, float* __restrict__ out)
{
    int tid = threadIdx.x;
    float m = 0.f;
    for (int i = tid; i < GN; i += 1024) m = fmaxf(m, hp[i*HPS + 16]);
#pragma unroll
    for (int s = 1; s < 64; s <<= 1) m = fmaxf(m, __shfl_xor(m, s, 64));
    __shared__ float ws[16];
    if ((tid & 63) == 0) ws[tid >> 6] = m;
    __syncthreads();
    if (tid < 16) {
        float v = ws[tid];
#pragma unroll
        for (int s = 1; s < 16; s <<= 1) v = fmaxf(v, __shfl_xor(v, s, 16));
        if (tid == 0) *out = v;
    }
}

// ---------------------------------------------------------------------------
// Measure the 32x32x16 C/D attribution empirically:
//  c1 = mfma(enc,ones): c1[reg]/16-1 = rho (lrow of A-lane feeding the row)
//  c2 = mfma(ones,enc): c2[reg]/16-1 = lam (lrow of B-lane feeding the col)
// k-arrangement cancels in the k-sum. Validated; failure -> pbad -> rescue.
__global__ void probe_kernel(int* __restrict__ table, int* __restrict__ pbad)
{
    const int lane = threadIdx.x;               // 64 threads, 1 block
    const int lrow = lane & 31;
    const short one = f2bs(1.f);
    v8s vone, venc;
#pragma unroll
    for (int e = 0; e < 8; ++e) { vone[e] = one; venc[e] = f2bs((float)(lrow + 1)); }
    const f32x16 z = {0.f,0.f,0.f,0.f,0.f,0.f,0.f,0.f,0.f,0.f,0.f,0.f,0.f,0.f,0.f,0.f};

    f32x16 c1 = __builtin_amdgcn_mfma_f32_32x32x16_bf16(venc, vone, z, 0, 0, 0);
    f32x16 c2 = __builtin_amdgcn_mfma_f32_32x32x16_bf16(vone, venc, z, 0, 0, 0);
    int badl = 0;
#pragma unroll
    for (int reg = 0; reg < 16; ++reg) {
        float fr = c1[reg] * 0.0625f - 1.f;
        float fl = c2[reg] * 0.0625f - 1.f;
        int ri = (int)floorf(fr + 0.5f);
        int li = (int)floorf(fl + 0.5f);
        if (fabsf(fr - (float)ri) > 1e-3f || (unsigned)ri > 31u ||
            fabsf(fl - (float)li) > 1e-3f || (unsigned)li > 31u) badl = 1;
        table[lane*16 + reg] = (ri & 255) | ((li & 255) << 8);
    }
    unsigned long long bm = __ballot(badl != 0);
    if (lane == 0) *pbad = (bm != 0ull) ? 1 : 0;
}

// ---------------------------------------------------------------------------
// MFMA kNN, layout-proof sq folding:
//   S1 = mfma(Asq, ONES, 0)          -> S1[reg] = sq_row   (any k-map)
//   c  = mfma(ONES, Bsq, S1)         -> + sq_col           (any k-map)
//   c += -2*(aa+ab+ba) via 3 MFMAs   -> c[reg] = d~        (pairing cancels)
// rho/lam (probed) used only for attribution. Self-test all 16 regs.
__global__ __launch_bounds__(256, 2) void knn10_kernel(
    const float* __restrict__ hp,
    const unsigned short* __restrict__ ha, const unsigned short* __restrict__ hb,
    const unsigned short* __restrict__ hs, const float* __restrict__ sqm,
    const int* __restrict__ table, const int* __restrict__ pbad,
    int* __restrict__ idxout, int* __restrict__ flags)
{
    __shared__ float    smp[RPB*SSTR];
    __shared__ int      bufj[RPB*BSTR];
    __shared__ unsigned cnt[RPB];
    __shared__ float    t16s[RPB];
    __shared__ int      badsh;

    const int tid   = threadIdx.x;
    const int w     = tid >> 6;
    const int lane  = tid & 63;
    const int lrow  = lane & 31;
    const int lhalf = lane >> 5;
    const int r0    = blockIdx.x * RPB;
    const int gbad  = *pbad;
    const float sqmax = *sqm;
    const short one = f2bs(1.f);
    const f32x16 z = {0.f,0.f,0.f,0.f,0.f,0.f,0.f,0.f,0.f,0.f,0.f,0.f,0.f,0.f,0.f,0.f};

    if (tid == 0) badsh = 0;
    if (tid < RPB) cnt[tid] = 0;
    __syncthreads();

    int pk[16];
    {
        const int4* tp = (const int4*)(table + lane*16);
        int4 a = tp[0], b = tp[1], c = tp[2], d = tp[3];
        pk[0]=a.x; pk[1]=a.y; pk[2]=a.z; pk[3]=a.w;
        pk[4]=b.x; pk[5]=b.y; pk[6]=b.z; pk[7]=b.w;
        pk[8]=c.x; pk[9]=c.y; pk[10]=c.z; pk[11]=c.w;
        pk[12]=d.x; pk[13]=d.y; pk[14]=d.z; pk[15]=d.w;
    }

    // A-side fragments (naive positions; Gram pairing cancels)
    v8s Aa, Ab, Asq, Aones;
    {
        const int base = (r0 + lrow) * 16;
        const unsigned si = *(const unsigned*)(hs + (r0 + lrow)*2);
#pragma unroll
        for (int e = 0; e < 8; ++e) {
            Aa[e] = neg2bf(ha[base + 8*lhalf + e]);
            Ab[e] = neg2bf(hb[base + 8*lhalf + e]);
            Aones[e] = one;
            short v = 0;
            if (lhalf == 0 && e == 0) v = (short)(si & 0xFFFFu);
            if (lhalf == 0 && e == 1) v = (short)(si >> 16);
            Asq[e] = v;
        }
    }
    // S1[reg] = sq_row (bf16-split sum), layout-proof (B = all ones)
    const f32x16 S1 = __builtin_amdgcn_mfma_f32_32x32x16_bf16(Asq, Aones, z, 0, 0, 0);

    float srow[16], Er[16];
#pragma unroll
    for (int reg = 0; reg < 16; ++reg) {
        const int rho = pk[reg] & 255;
        srow[reg] = hp[(r0 + rho)*HPS + 16];
        Er[reg] = fmaf(EREL, srow[reg] + sqmax, EABS);
    }

    // ---- phase A: sampled columns (stride 4); per-(thread,reg) top-2 of d~
    float m1[16], m2[16];
#pragma unroll
    for (int e = 0; e < 16; ++e) { m1[e] = INFF; m2[e] = INFF; }

    for (int t = 0; t < 32; ++t) {
        const int tb = (w + 4*t)*32;
        const int jb = 4*(tb + lrow);
        v8s Ba = *(const v8s*)(ha + jb*16 + 8*lhalf);
        v8s Bb = *(const v8s*)(hb + jb*16 + 8*lhalf);
        const unsigned sj = *(const unsigned*)(hs + jb*2);
        v8s Bsq = {0,0,0,0,0,0,0,0};
        if (lhalf == 0) {
            Bsq[0] = (short)(sj & 0xFFFFu);
            Bsq[1] = (short)(sj >> 16);
        }
        f32x16 c = __builtin_amdgcn_mfma_f32_32x32x16_bf16(Aones, Bsq, S1, 0, 0, 0);
        c = __builtin_amdgcn_mfma_f32_32x32x16_bf16(Aa, Ba, c, 0, 0, 0);
        c = __builtin_amdgcn_mfma_f32_32x32x16_bf16(Aa, Bb, c, 0, 0, 0);
        c = __builtin_amdgcn_mfma_f32_32x32x16_bf16(Ab, Ba, c, 0, 0, 0);
        if (t == 0) {
            // self-test: every accumulator vs exact f32 distance of its pair
#pragma unroll
            for (int reg = 0; reg < 16; ++reg) {
                const int rho = pk[reg] & 255, lam = (pk[reg] >> 8) & 255;
                const int jc = 4*(w*32 + lam);
                if (jc != r0 + rho) {
                    LOAD_HI(hp + (r0 + rho)*HPS);
                    float dex = distt(hi, sqi, hp + jc*HPS);
                    if (!(fabsf(c[reg] - dex) <= Er[reg])) badsh = 1;
                }
            }
        }
#pragma unroll
        for (int reg = 0; reg < 16; ++reg) {
            const int rho = pk[reg] & 255, lam = (pk[reg] >> 8) & 255;
            float v = c[reg];
            if (4*(tb + lam) == r0 + rho) v = INFF;   // exclude self
            float hh = fmaxf(m1[reg], v);
            m1[reg] = fminf(m1[reg], v);
            m2[reg] = fminf(m2[reg], hh);
        }
    }
    __syncthreads();
#pragma unroll
    for (int reg = 0; reg < 16; ++reg) {
        const int rho = pk[reg] & 255, lam = (pk[reg] >> 8) & 255;
        smp[rho*SSTR + w*64 + lam*2 + 0] = m1[reg];
        smp[rho*SSTR + w*64 + lam*2 + 1] = m2[reg];
    }
    __syncthreads();

    // ---- merge: 16th smallest of 256 sample d~ per row (8 lanes/row)
    const int mr = tid >> 3, g = tid & 7;
    {
        float sv[32];
#pragma unroll
        for (int e = 0; e < 8; ++e) {
            float4 u = *(const float4*)(smp + mr*SSTR + g*32 + e*4);
            sv[e*4+0] = u.x; sv[e*4+1] = u.y; sv[e*4+2] = u.z; sv[e*4+3] = u.w;
        }
        float tv = INFF;
#pragma unroll
        for (int k = 0; k < 16; ++k) {
            float md = sv[0]; int ms = 0;
#pragma unroll
            for (int e = 1; e < 32; ++e) { bool cs = (sv[e] < md); md = cs ? sv[e] : md; ms = cs ? e : ms; }
            float rv = md; int rl = g;
#pragma unroll
            for (int mm = 1; mm <= 4; mm <<= 1) {
                float ov = __shfl_xor(rv, mm, 8);
                int   ol = __shfl_xor(rl, mm, 8);
                bool cs = (ov < rv) || (ov == rv && ol < rl);
                rv = cs ? ov : rv; rl = cs ? ol : rl;
            }
            tv = rv;
            if (rl == g) {
#pragma unroll
                for (int e = 0; e < 32; ++e) if (e == ms) sv[e] = INFF;
            }
        }
        if (g == 0) t16s[mr] = tv;
    }
    __syncthreads();

    // TR = tau + 2*Er: |d~ - d| <= Er both in tau and in the candidate -> superset
    float TR[16];
#pragma unroll
    for (int reg = 0; reg < 16; ++reg)
        TR[reg] = t16s[pk[reg] & 255] + 2.f*Er[reg];

    // ---- phase B: full scan; collect d~ <= TR (sampled qualifiers re-qualify
    // bit-identically -> cnt >= 16; self excluded by index)
    for (int t = 0; t < 128; ++t) {
        const int tb = (w + 4*t)*32;
        const int jb = tb + lrow;
        v8s Ba = *(const v8s*)(ha + jb*16 + 8*lhalf);
        v8s Bb = *(const v8s*)(hb + jb*16 + 8*lhalf);
        const unsigned sj = *(const unsigned*)(hs + jb*2);
        v8s Bsq = {0,0,0,0,0,0,0,0};
        if (lhalf == 0) {
            Bsq[0] = (short)(sj & 0xFFFFu);
            Bsq[1] = (short)(sj >> 16);
        }
        f32x16 c = __builtin_amdgcn_mfma_f32_32x32x16_bf16(Aones, Bsq, S1, 0, 0, 0);
        c = __builtin_amdgcn_mfma_f32_32x32x16_bf16(Aa, Ba, c, 0, 0, 0);
        c = __builtin_amdgcn_mfma_f32_32x32x16_bf16(Aa, Bb, c, 0, 0, 0);
        c = __builtin_amdgcn_mfma_f32_32x32x16_bf16(Ab, Ba, c, 0, 0, 0);
#pragma unroll
        for (int reg = 0; reg < 16; ++reg) {
            if (c[reg] <= TR[reg]) {
                const int rho = pk[reg] & 255, lam = (pk[reg] >> 8) & 255;
                const int j = tb + lam;
                if (j != r0 + rho) {
                    unsigned pos = atomicAdd(&cnt[rho], 1u);
                    if (pos < CAP) bufj[rho*BSTR + pos] = j;
                }
            }
        }
    }
    __syncthreads();

    // ---- exact f32 recheck + top-16 select ((d,j) order, ref-identical)
    {
        const unsigned cc  = cnt[mr];
        const unsigned lim = cc < CAP ? cc : CAP;
        LOAD_HI(hp + (r0 + mr)*HPS);
        float sd[20]; int sj[20];
#pragma unroll
        for (int e = 0; e < 20; ++e) {
            unsigned p = (unsigned)g + 8u*e;
            bool v = p < lim;
            if (v) {
                int j = bufj[mr*BSTR + p];
                sj[e] = j;
                sd[e] = distt(hi, sqi, hp + j*HPS);
            } else { sd[e] = INFF; sj[e] = 0x7fffffff; }
        }
#pragma unroll
        for (int k = 0; k < GK; ++k) {
            float md = sd[0]; int mj = sj[0]; int ms = 0;
#pragma unroll
            for (int e = 1; e < 20; ++e) {
                bool cs = (sd[e] < md) || (sd[e] == md && sj[e] < mj);
                md = cs ? sd[e] : md; mj = cs ? sj[e] : mj; ms = cs ? e : ms;
            }
            float rd = md; int rj = mj;
#pragma unroll
            for (int mm = 1; mm <= 4; mm <<= 1) {
                float od = __shfl_xor(rd, mm, 8);
                int   oj = __shfl_xor(rj, mm, 8);
                bool cs = (od < rd) || (od == rd && oj < rj);
                rd = cs ? od : rd; rj = cs ? oj : rj;
            }
            if (g == 0) idxout[(r0 + mr)*GK + k] = rj;
            if (rd == md && rj == mj) {
#pragma unroll
                for (int e = 0; e < 20; ++e) if (e == ms) { sd[e] = INFF; sj[e] = 0x7fffffff; }
            }
        }
        if (g == 0)
            flags[r0 + mr] = (cc > CAP || cc < 16u || badsh || gbad) ? 1 : 0;
    }
}

// ---------------------------------------------------------------------------
// Exact full-scan fallback for flagged rows (16 waves; slow-but-correct).
__global__ __launch_bounds__(1024) void rescue_kernel(
    const float* __restrict__ hp, const int* __restrict__ flags,
    int* __restrict__ idxout)
{
    const int lane = threadIdx.x & 63;
    const int ww   = threadIdx.x >> 6;
    const int r0 = blockIdx.x * RPB;
    int f = (lane < RPB) ? flags[r0 + lane] : 0;
    if (__ballot(f != 0) == 0ull) return;
    for (int rr = ww; rr < RPB; rr += 16) {
        if (flags[r0 + rr] == 0) continue;
        const int row = r0 + rr;
        LOAD_HI(hp + row * HPS);
        float topd[GK]; int topi[GK];
#pragma unroll
        for (int s = 0; s < GK; ++s) { topd[s] = INFF; topi[s] = -1; }
        float mx = INFF; int mxs = 0;
        for (int s = 0; s < GN/64; ++s) {
            int j = lane + (s << 6);
            float d = distt(hi, sqi, hp + j * HPS);
            if (j == row) d = INFF;
            if (d < mx) {
#pragma unroll
                for (int e = 0; e < GK; ++e) { bool cs = (e == mxs); topd[e] = cs ? d : topd[e]; topi[e] = cs ? j : topi[e]; }
                mx = topd[0]; mxs = 0;
#pragma unroll
                for (int e = 1; e < GK; ++e) { bool cs = (topd[e] >= mx); mx = cs ? topd[e] : mx; mxs = cs ? e : mxs; }
            }
        }
#pragma unroll
        for (int t = 0; t < GK; ++t) {
            float md = topd[0]; int mj = topi[0]; int ms = 0;
#pragma unroll
            for (int e = 1; e < GK; ++e) {
                bool cs = (topd[e] < md) || (topd[e] == md && topi[e] < mj);
                md = cs ? topd[e] : md; mj = cs ? topi[e] : mj; ms = cs ? e : ms;
            }
            float rd = md; int rj = mj;
#pragma unroll
            for (int m = 1; m <= 32; m <<= 1) {
                float od = __shfl_xor(rd, m, 64);
                int   oj = __shfl_xor(rj, m, 64);
                bool cs = (od < rd) || (od == rd && oj < rj);
                rd = cs ? od : rd; rj = cs ? oj : rj;
            }
            if (lane == 0) idxout[row*GK + t] = rj;
            if (rd == md && rj == mj) {
#pragma unroll
                for (int e = 0; e < GK; ++e) if (e == ms) { topd[e] = INFF; topi[e] = 0x7fffffff; }
            }
        }
    }
}

// ---------------------------------------------------------------------------
__global__ __launch_bounds__(256) void edgeconv_kernel(
    const float* __restrict__ hin, const int* __restrict__ idx,
    const float* __restrict__ W1, const float* __restrict__ b1,
    const float* __restrict__ W2, const float* __restrict__ b2,
    float* __restrict__ hout)
{
    __shared__ float sW1[2*GH*GH], sW2[GH*GH], sb1[GH], sb2[GH];
    const int tid = threadIdx.x;
    for (int t = tid; t < 2*GH*GH; t += 256) sW1[t] = W1[t];
    for (int t = tid; t < GH*GH;  t += 256) sW2[t] = W2[t];
    if (tid < GH) { sb1[tid] = b1[tid]; sb2[tid] = b2[tid]; }
    __syncthreads();

    const int t4 = tid & 3;
    const int i = blockIdx.x * 64 + (tid >> 2);

    LOAD_HI(hin + i * HPS);
    (void)sqi;
    float ci[GH];
#pragma unroll
    for (int c = 0; c < GH; ++c) {
        float s = sb1[c];
#pragma unroll
        for (int d = 0; d < GH; ++d) s = fmaf(hi[d], sW1[d*GH+c], s);
        ci[c] = s;
    }
    float acc[GH];
#pragma unroll
    for (int c = 0; c < GH; ++c) acc[c] = 0.f;

    const int4 jj = *(const int4*)(idx + i*GK + t4*4);
    const int js[4] = { jj.x, jj.y, jj.z, jj.w };
#pragma unroll
    for (int nn = 0; nn < 4; ++nn) {
        const int j = js[nn];
        float dj[GH];
        {
            const float* hv = hin + j * HPS;
            float4 A = *(const float4*)(hv + 0);
            float4 B = *(const float4*)(hv + 4);
            float4 C = *(const float4*)(hv + 8);
            float4 D = *(const float4*)(hv + 12);
            dj[0]=A.x-hi[0]; dj[1]=A.y-hi[1]; dj[2]=A.z-hi[2]; dj[3]=A.w-hi[3];
            dj[4]=B.x-hi[4]; dj[5]=B.y-hi[5]; dj[6]=B.z-hi[6]; dj[7]=B.w-hi[7];
            dj[8]=C.x-hi[8]; dj[9]=C.y-hi[9]; dj[10]=C.z-hi[10]; dj[11]=C.w-hi[11];
            dj[12]=D.x-hi[12]; dj[13]=D.y-hi[13]; dj[14]=D.z-hi[14]; dj[15]=D.w-hi[15];
        }
        float msg[GH];
#pragma unroll
        for (int c = 0; c < GH; ++c) {
            float s = ci[c];
#pragma unroll
            for (int d = 0; d < GH; ++d) s = fmaf(dj[d], sW1[(GH+d)*GH+c], s);
            msg[c] = fmaxf(s, 0.f);
        }
#pragma unroll
        for (int c2 = 0; c2 < GH; ++c2) {
            float s = acc[c2];
#pragma unroll
            for (int c = 0; c < GH; ++c) s = fmaf(msg[c], sW2[c*GH+c2], s);
            acc[c2] = s;
        }
    }
#pragma unroll
    for (int c = 0; c < GH; ++c) {
        acc[c] += __shfl_xor(acc[c], 1);
        acc[c] += __shfl_xor(acc[c], 2);
    }
    if (t4 == 0) {
        float* orow = hout + i * HPS;
        float sq = 0.f;
#pragma unroll
        for (int c = 0; c < GH; ++c) {
            float v = acc[c] * (1.f/16.f) + sb2[c];
            orow[c] = v;
            sq = fmaf(v, v, sq);
        }
        orow[16] = sq;
    }
}

// ---------------------------------------------------------------------------
__global__ __launch_bounds__(256) void out_kernel(
    const float* __restrict__ hbase, const float* __restrict__ W,
    const float* __restrict__ b, void* __restrict__ out,
    const int* __restrict__ flag)
{
    int i = blockIdx.x * 256 + threadIdx.x;
    float a0 = b[0], a1 = b[1], a2 = b[2];
#pragma unroll
    for (int l = 0; l < GL; ++l) {
        const float* hp = hbase + l * GN * HPS + i * HPS;
#pragma unroll
        for (int c = 0; c < GH; ++c) {
            const float v = hp[c];
            const float* wr = W + (l * GH + c) * 3;
            a0 = fmaf(v, wr[0], a0);
            a1 = fmaf(v, wr[1], a1);
            a2 = fmaf(v, wr[2], a2);
        }
    }
    if (*flag) {
        __hip_bfloat16* o = (__hip_bfloat16*)out;
        o[i*3+0] = __float2bfloat16(a0);
        o[i*3+1] = __float2bfloat16(a1);
        o[i*3+2] = __float2bfloat16(a2);
    } else {
        float* o = (float*)out;
        o[i*3+0] = a0; o[i*3+1] = a1; o[i*3+2] = a2;
    }
}

// ---------------------------------------------------------------------------
extern "C" void kernel_launch(void* const* d_in, const int* in_sizes, int n_in,
                              void* d_out, int out_size, void* d_ws, size_t ws_size,
                              hipStream_t stream)
{
    float* wsf  = (float*)d_ws;
    int* idxb   = (int*)(wsf + OFF_IDX);
    int* flagsb = (int*)(wsf + OFF_FLAGS);
    int* dflag  = (int*)(wsf + OFF_DFLAG);
    unsigned short* ha = (unsigned short*)(wsf + OFF_HA);
    unsigned short* hb = (unsigned short*)(wsf + OFF_HB);
    unsigned short* hs = (unsigned short*)(wsf + OFF_HS);
    int* tab    = (int*)(wsf + OFF_TAB);
    int* pbad   = (int*)(wsf + OFF_PBAD);
    float* sqmp = wsf + OFF_SQM;

    detect_kernel<<<1, 64, 0, stream>>>((const unsigned short*)d_in[0], dflag);
    probe_kernel<<<1, 64, 0, stream>>>(tab, pbad);

    const int segoff[9] = {OFF_XF, OFF_EMBW, OFF_EMBB, OFF_W1, OFF_B1,
                           OFF_W2, OFF_B2, OFF_OW, OFF_OB};
    const int segn[9]   = {GN*3, 3*GH, GH, GL*2*GH*GH, GL*GH,
                           GL*GH*GH, GL*GH, GL*GH*3, 3};
    for (int s = 0; s < 9; ++s)
        convert_kernel<<<(segn[s] + 255)/256, 256, 0, stream>>>(
            d_in[s], wsf + segoff[s], segn[s], dflag);

    embed_kernel<<<GN/256, 256, 0, stream>>>(
        wsf + OFF_XF, wsf + OFF_EMBW, wsf + OFF_EMBB, wsf + OFF_H);

    for (int l = 0; l < GL; ++l) {
        const float* hin = wsf + OFF_H + l*GN*HPS;
        float* hout      = wsf + OFF_H + (l+1)*GN*HPS;
        bfsplit_kernel<<<GN*GH/256, 256, 0, stream>>>(hin, ha, hb, hs);
        sqmax_kernel<<<1, 1024, 0, stream>>>(hin, sqmp);
        knn10_kernel<<<GN/RPB, 256, 0, stream>>>(hin, ha, hb, hs, sqmp,
                                                 tab, pbad, idxb, flagsb);
        rescue_kernel<<<GN/RPB, 1024, 0, stream>>>(hin, flagsb, idxb);
        edgeconv_kernel<<<GN/64, 256, 0, stream>>>(hin, idxb,
            wsf + OFF_W1 + l*2*GH*GH, wsf + OFF_B1 + l*GH,
            wsf + OFF_W2 + l*GH*GH,  wsf + OFF_B2 + l*GH, hout);
    }

    out_kernel<<<GN/256, 256, 0, stream>>>(
        wsf + OFF_H + GN*HPS, wsf + OFF_OW, wsf + OFF_OB, d_out, dflag);
}

// Round 11
// 1662.263 us; speedup vs baseline: 2.4983x; 2.4983x over previous
//
#include <hip/hip_runtime.h>
#include <hip/hip_bf16.h>

#define GN 16384
#define GH 16
#define GK 16
#define GL 4
#define HPS 20            // padded h row: 16 features + sq + 3 pad (80 B)

#define TPB 256           // knn block: 8 row-quads x 32 col-slots
#define RPB 32            // rows per knn block
#define CAP 160           // collect buffer capacity per row
#define BSTR 161          // buffer row stride (floats)
#define SSTR2 68          // phase-1 merge row stride (64 vals + pad, 16B-mult)
#define TILE_C 256        // columns per LDS tile
#define TILE_F (TILE_C*HPS)
#define LDS_TILE (2*RPB*BSTR + 2*RPB)
#define LDS_TOT  (LDS_TILE + TILE_F)    // 15488 floats = 60.5 KB -> 2 blk/CU

#define INFF __builtin_inff()

// workspace float-offsets
#define OFF_H     0
#define OFF_IDX   (5*GN*HPS)
#define OFF_FLAGS (OFF_IDX + GN*GK)
#define OFF_XF    (OFF_FLAGS + GN)
#define OFF_EMBW  (OFF_XF + GN*3)
#define OFF_EMBB  (OFF_EMBW + 3*GH)
#define OFF_W1    (OFF_EMBB + GH)
#define OFF_B1    (OFF_W1 + GL*2*GH*GH)
#define OFF_W2    (OFF_B1 + GL*GH)
#define OFF_B2    (OFF_W2 + GL*GH*GH)
#define OFF_OW    (OFF_B2 + GL*GH)
#define OFF_OB    (OFF_OW + GL*GH*3)
#define OFF_DFLAG (OFF_OB + 4)

// ---------------------------------------------------------------------------
__global__ void detect_kernel(const unsigned short* __restrict__ raw,
                              int* __restrict__ flag)
{
    if (threadIdx.x == 0 && blockIdx.x == 0) {
        int cnt = 0;
        for (int i = 0; i < 64; ++i) {
            unsigned int bits = ((unsigned int)raw[2*i]) << 16;
            float v = __uint_as_float(bits);
            float a = fabsf(v);
            if (a > 1e-4f && a < 50.f) ++cnt;
        }
        *flag = (cnt >= 32) ? 1 : 0;   // 1 = inputs are bf16
    }
}

__global__ void convert_kernel(const void* __restrict__ src,
                               float* __restrict__ dst, int n,
                               const int* __restrict__ flag)
{
    int i = blockIdx.x * 256 + threadIdx.x;
    if (i >= n) return;
    if (*flag)
        dst[i] = __bfloat162float(((const __hip_bfloat16*)src)[i]);
    else
        dst[i] = ((const float*)src)[i];
}

// ---------------------------------------------------------------------------
__device__ __forceinline__ float distt(const float hi[16], float sqi,
                                       const float* __restrict__ hj)
{
    float4 A = *(const float4*)(hj + 0);
    float4 B = *(const float4*)(hj + 4);
    float4 C = *(const float4*)(hj + 8);
    float4 D = *(const float4*)(hj + 12);
    float sqj = hj[16];
    float d0 = hi[0]*A.x;
    float d1 = hi[1]*A.y;
    d0 = fmaf(hi[2],  A.z, d0);  d1 = fmaf(hi[3],  A.w, d1);
    d0 = fmaf(hi[4],  B.x, d0);  d1 = fmaf(hi[5],  B.y, d1);
    d0 = fmaf(hi[6],  B.z, d0);  d1 = fmaf(hi[7],  B.w, d1);
    d0 = fmaf(hi[8],  C.x, d0);  d1 = fmaf(hi[9],  C.y, d1);
    d0 = fmaf(hi[10], C.z, d0);  d1 = fmaf(hi[11], C.w, d1);
    d0 = fmaf(hi[12], D.x, d0);  d1 = fmaf(hi[13], D.y, d1);
    d0 = fmaf(hi[14], D.z, d0);  d1 = fmaf(hi[15], D.w, d1);
    return fmaf(-2.f, d0 + d1, sqi + sqj);
}

#define LOAD_HI(ptr)                                                        \
    float hi[16]; float sqi;                                                \
    {                                                                       \
        const float* _hr = (ptr);                                           \
        float4 A = *(const float4*)(_hr + 0);                               \
        float4 B = *(const float4*)(_hr + 4);                               \
        float4 C = *(const float4*)(_hr + 8);                               \
        float4 D = *(const float4*)(_hr + 12);                              \
        hi[0]=A.x; hi[1]=A.y; hi[2]=A.z; hi[3]=A.w;                         \
        hi[4]=B.x; hi[5]=B.y; hi[6]=B.z; hi[7]=B.w;                         \
        hi[8]=C.x; hi[9]=C.y; hi[10]=C.z; hi[11]=C.w;                       \
        hi[12]=D.x; hi[13]=D.y; hi[14]=D.z; hi[15]=D.w;                     \
        sqi = _hr[16];                                                      \
    }

// ---------------------------------------------------------------------------
__global__ __launch_bounds__(256) void embed_kernel(
    const float* __restrict__ xf, const float* __restrict__ W,
    const float* __restrict__ b, float* __restrict__ h0)
{
    int i = blockIdx.x * 256 + threadIdx.x;
    float x0 = xf[i*3+0], x1 = xf[i*3+1], x2 = xf[i*3+2];
    float* orow = h0 + i * HPS;
    float sq = 0.f;
#pragma unroll
    for (int c = 0; c < GH; ++c) {
        float t = b[c];
        t = fmaf(x0, W[0*GH+c], t);
        t = fmaf(x1, W[1*GH+c], t);
        t = fmaf(x2, W[2*GH+c], t);
        t = fmaxf(t, 0.f);
        orow[c] = t;
        sq = fmaf(t, t, sq);
    }
    orow[16] = sq;
}

// ---------------------------------------------------------------------------
// Exact kNN, VALU path: 2-phase threshold-collect, LDS tiles, 4-row register
// blocking. 256-thr blocks (not 1024) so the allocator grants >64 VGPRs
// (m97 precedent: 164 VGPR @ 256 thr). col = s + 32*cc => ds_read_b128 lanes
// at 80 B stride => disjoint bank-quads, conflict-free.
__global__ void knn11_kernel(
    const float* __restrict__ hp, int* __restrict__ idxout,
    int* __restrict__ flags)
{
    __shared__ float lds[LDS_TOT];
    float*    bufd = lds;
    int*      bufj = (int*)(lds + RPB*BSTR);
    unsigned* cnt  = (unsigned*)(lds + 2*RPB*BSTR);
    float*    tau  = lds + 2*RPB*BSTR + RPB;
    float*    tile = lds + LDS_TILE;
    float4*   tile4 = (float4*)tile;
    const float4* hp4 = (const float4*)hp;

    const int tid = threadIdx.x;
    const int q   = tid & 7;            // row-quad (rows q*4..q*4+3)
    const int s   = tid >> 3;           // col-slot 0..31
    const int rb  = blockIdx.x * RPB;
    const int r0  = rb + q * 4;

    if (tid < RPB) cnt[tid] = 0;

    // ---- load 4 center rows into registers
    float hi[4][16]; float sqi[4];
#pragma unroll
    for (int rr = 0; rr < 4; ++rr) {
        const float* hr = hp + (r0 + rr) * HPS;
        float4 A = *(const float4*)(hr + 0);
        float4 B = *(const float4*)(hr + 4);
        float4 C = *(const float4*)(hr + 8);
        float4 D = *(const float4*)(hr + 12);
        hi[rr][0]=A.x; hi[rr][1]=A.y; hi[rr][2]=A.z; hi[rr][3]=A.w;
        hi[rr][4]=B.x; hi[rr][5]=B.y; hi[rr][6]=B.z; hi[rr][7]=B.w;
        hi[rr][8]=C.x; hi[rr][9]=C.y; hi[rr][10]=C.z; hi[rr][11]=C.w;
        hi[rr][12]=D.x; hi[rr][13]=D.y; hi[rr][14]=D.z; hi[rr][15]=D.w;
        sqi[rr] = hr[16];
    }

    // distance for 4 rows vs staged col; self excluded
#define DIST4(hjp, jglob, dd)                                               \
    {                                                                       \
        const float* _hj = (hjp);                                           \
        float4 A = *(const float4*)(_hj + 0);                               \
        float4 B = *(const float4*)(_hj + 4);                               \
        float4 C = *(const float4*)(_hj + 8);                               \
        float4 D = *(const float4*)(_hj + 12);                              \
        float sqj = _hj[16];                                                \
        _Pragma("unroll")                                                   \
        for (int rr = 0; rr < 4; ++rr) {                                    \
            float d0 = hi[rr][0]*A.x;                                       \
            float d1 = hi[rr][1]*A.y;                                       \
            d0 = fmaf(hi[rr][2],  A.z, d0);  d1 = fmaf(hi[rr][3],  A.w, d1);\
            d0 = fmaf(hi[rr][4],  B.x, d0);  d1 = fmaf(hi[rr][5],  B.y, d1);\
            d0 = fmaf(hi[rr][6],  B.z, d0);  d1 = fmaf(hi[rr][7],  B.w, d1);\
            d0 = fmaf(hi[rr][8],  C.x, d0);  d1 = fmaf(hi[rr][9],  C.y, d1);\
            d0 = fmaf(hi[rr][10], C.z, d0);  d1 = fmaf(hi[rr][11], C.w, d1);\
            d0 = fmaf(hi[rr][12], D.x, d0);  d1 = fmaf(hi[rr][13], D.y, d1);\
            d0 = fmaf(hi[rr][14], D.z, d0);  d1 = fmaf(hi[rr][15], D.w, d1);\
            dd[rr] = fmaf(-2.f, d0 + d1, sqi[rr] + sqj);                    \
        }                                                                   \
        unsigned u = (unsigned)((jglob) - r0);                              \
        if (u < 4u) {                                                       \
            _Pragma("unroll")                                               \
            for (int rr = 0; rr < 4; ++rr)                                  \
                if (u == (unsigned)rr) dd[rr] = INFF;                       \
        }                                                                   \
    }

    // ---- phase 1: sample every 4th column; branchless per-row top-2 stream
    float m1[4], m2[4];
#pragma unroll
    for (int rr = 0; rr < 4; ++rr) { m1[rr] = INFF; m2[rr] = INFF; }
    for (int t = 0; t < 16; ++t) {
        __syncthreads();
        for (int v = tid; v < TILE_C*5; v += TPB) {
            int c = v / 5, f = v - 5*c;
            tile4[v] = hp4[20*(t*256 + c) + f];
        }
        __syncthreads();
#pragma unroll 2
        for (int cc = 0; cc < 8; ++cc) {
            const int lc = s + 32*cc;
            const int j = 4*(t*256 + lc);
            float dd[4];
            DIST4(tile + lc*HPS, j, dd);
#pragma unroll
            for (int rr = 0; rr < 4; ++rr) {
                float h2 = fmaxf(m1[rr], dd[rr]);
                m1[rr] = fminf(m1[rr], dd[rr]);
                m2[rr] = fminf(m2[rr], h2);
            }
        }
    }
    __syncthreads();
    // stash per-(thread,row) top-2 (overlays buffer region; 16B-aligned rows)
#pragma unroll
    for (int rr = 0; rr < 4; ++rr) {
        lds[(q*4+rr)*SSTR2 + s*2 + 0] = m1[rr];
        lds[(q*4+rr)*SSTR2 + s*2 + 1] = m2[rr];
    }
    __syncthreads();

    // ---- phase 1b: per-row merge (8 lanes/row): tau = 16th smallest sample
    const int mr = tid >> 3, g = tid & 7;
    {
        float sv[8];
        float4 u0 = *(const float4*)(lds + mr*SSTR2 + g*8);
        float4 u1 = *(const float4*)(lds + mr*SSTR2 + g*8 + 4);
        sv[0]=u0.x; sv[1]=u0.y; sv[2]=u0.z; sv[3]=u0.w;
        sv[4]=u1.x; sv[5]=u1.y; sv[6]=u1.z; sv[7]=u1.w;
        float tv = INFF;
#pragma unroll
        for (int k = 0; k < 16; ++k) {
            float md = sv[0]; int ms = 0;
#pragma unroll
            for (int e = 1; e < 8; ++e) { bool cs = (sv[e] < md); md = cs ? sv[e] : md; ms = cs ? e : ms; }
            float rv = md; int rl = g;
#pragma unroll
            for (int mm = 1; mm <= 4; mm <<= 1) {
                float ov = __shfl_xor(rv, mm, 8);
                int   ol = __shfl_xor(rl, mm, 8);
                bool cs = (ov < rv) || (ov == rv && ol < rl);
                rv = cs ? ov : rv; rl = cs ? ol : rl;
            }
            tv = rv;
            if (rl == g) {
#pragma unroll
                for (int e = 0; e < 8; ++e) if (e == ms) sv[e] = INFF;
            }
        }
        if (g == 0) tau[mr] = tv;
    }
    __syncthreads();

    // ---- phase 2: full scan via contiguous tiles; collect d <= tau.
    // Sampled qualifiers re-qualify bit-identically -> cnt >= 16 guaranteed.
    float tau4[4];
#pragma unroll
    for (int rr = 0; rr < 4; ++rr) tau4[rr] = tau[q*4+rr];
    for (int k = 0; k < GN/TILE_C; ++k) {
        __syncthreads();
        for (int v = tid; v < TILE_C*5; v += TPB)
            tile4[v] = hp4[k*(TILE_C*5) + v];
        __syncthreads();
#pragma unroll 2
        for (int cc = 0; cc < 8; ++cc) {
            const int lc = s + 32*cc;
            const int j = k*TILE_C + lc;
            float dd[4];
            DIST4(tile + lc*HPS, j, dd);
            bool p0 = dd[0] <= tau4[0], p1 = dd[1] <= tau4[1];
            bool p2 = dd[2] <= tau4[2], p3 = dd[3] <= tau4[3];
            if (p0 | p1 | p2 | p3) {
#pragma unroll
                for (int rr = 0; rr < 4; ++rr) {
                    if (dd[rr] <= tau4[rr]) {
                        unsigned pos = atomicAdd(&cnt[q*4+rr], 1u);
                        if (pos < CAP) {
                            bufd[(q*4+rr)*BSTR + pos] = dd[rr];
                            bufj[(q*4+rr)*BSTR + pos] = j;
                        }
                    }
                }
            }
        }
    }
    __syncthreads();

    // ---- phase 3: exact top-16 per row (8 lanes/row, 20 entries each),
    // (d,j) lexicographic order == reference top_k tie-break
    {
        const unsigned c2  = cnt[mr];
        const unsigned lim = c2 < CAP ? c2 : CAP;
        float sd[20]; int sj[20];
#pragma unroll
        for (int e = 0; e < 20; ++e) {
            unsigned p = (unsigned)g + 8u*e;
            bool v = p < lim;
            sd[e] = v ? bufd[mr*BSTR + p] : INFF;
            sj[e] = v ? bufj[mr*BSTR + p] : 0x7fffffff;
        }
        const int rowg = rb + mr;
#pragma unroll
        for (int k = 0; k < GK; ++k) {
            float md = sd[0]; int mj = sj[0]; int ms = 0;
#pragma unroll
            for (int e = 1; e < 20; ++e) {
                bool cs = (sd[e] < md) || (sd[e] == md && sj[e] < mj);
                md = cs ? sd[e] : md; mj = cs ? sj[e] : mj; ms = cs ? e : ms;
            }
            float rd = md; int rj = mj;
#pragma unroll
            for (int mm = 1; mm <= 4; mm <<= 1) {
                float od = __shfl_xor(rd, mm, 8);
                int   oj = __shfl_xor(rj, mm, 8);
                bool cs = (od < rd) || (od == rd && oj < rj);
                rd = cs ? od : rd; rj = cs ? oj : rj;
            }
            if (g == 0) idxout[rowg*GK + k] = rj;
            if (rd == md && rj == mj) {
#pragma unroll
                for (int e = 0; e < 20; ++e) if (e == ms) { sd[e] = INFF; sj[e] = 0x7fffffff; }
            }
        }
        if (g == 0) flags[rowg] = (c2 > CAP || c2 < 16u) ? 1 : 0;
    }
#undef DIST4
}

// ---------------------------------------------------------------------------
// Exact full-scan fallback for flagged rows (16 waves; slow-but-correct).
__global__ __launch_bounds__(1024) void rescue_kernel(
    const float* __restrict__ hp, const int* __restrict__ flags,
    int* __restrict__ idxout)
{
    const int lane = threadIdx.x & 63;
    const int ww   = threadIdx.x >> 6;
    const int r0 = blockIdx.x * RPB;
    int f = (lane < RPB) ? flags[r0 + lane] : 0;
    if (__ballot(f != 0) == 0ull) return;
    for (int rr = ww; rr < RPB; rr += 16) {
        if (flags[r0 + rr] == 0) continue;
        const int row = r0 + rr;
        LOAD_HI(hp + row * HPS);
        float topd[GK]; int topi[GK];
#pragma unroll
        for (int s = 0; s < GK; ++s) { topd[s] = INFF; topi[s] = -1; }
        float mx = INFF; int mxs = 0;
        for (int s = 0; s < GN/64; ++s) {
            int j = lane + (s << 6);
            float d = distt(hi, sqi, hp + j * HPS);
            if (j == row) d = INFF;
            if (d < mx) {
#pragma unroll
                for (int e = 0; e < GK; ++e) { bool cs = (e == mxs); topd[e] = cs ? d : topd[e]; topi[e] = cs ? j : topi[e]; }
                mx = topd[0]; mxs = 0;
#pragma unroll
                for (int e = 1; e < GK; ++e) { bool cs = (topd[e] >= mx); mx = cs ? topd[e] : mx; mxs = cs ? e : mxs; }
            }
        }
#pragma unroll
        for (int t = 0; t < GK; ++t) {
            float md = topd[0]; int mj = topi[0]; int ms = 0;
#pragma unroll
            for (int e = 1; e < GK; ++e) {
                bool cs = (topd[e] < md) || (topd[e] == md && topi[e] < mj);
                md = cs ? topd[e] : md; mj = cs ? topi[e] : mj; ms = cs ? e : ms;
            }
            float rd = md; int rj = mj;
#pragma unroll
            for (int m = 1; m <= 32; m <<= 1) {
                float od = __shfl_xor(rd, m, 64);
                int   oj = __shfl_xor(rj, m, 64);
                bool cs = (od < rd) || (od == rd && oj < rj);
                rd = cs ? od : rd; rj = cs ? oj : rj;
            }
            if (lane == 0) idxout[row*GK + t] = rj;
            if (rd == md && rj == mj) {
#pragma unroll
                for (int e = 0; e < GK; ++e) if (e == ms) { topd[e] = INFF; topi[e] = 0x7fffffff; }
            }
        }
    }
}

// ---------------------------------------------------------------------------
__global__ __launch_bounds__(256) void edgeconv_kernel(
    const float* __restrict__ hin, const int* __restrict__ idx,
    const float* __restrict__ W1, const float* __restrict__ b1,
    const float* __restrict__ W2, const float* __restrict__ b2,
    float* __restrict__ hout)
{
    __shared__ float sW1[2*GH*GH], sW2[GH*GH], sb1[GH], sb2[GH];
    const int tid = threadIdx.x;
    for (int t = tid; t < 2*GH*GH; t += 256) sW1[t] = W1[t];
    for (int t = tid; t < GH*GH;  t += 256) sW2[t] = W2[t];
    if (tid < GH) { sb1[tid] = b1[tid]; sb2[tid] = b2[tid]; }
    __syncthreads();

    const int t4 = tid & 3;
    const int i = blockIdx.x * 64 + (tid >> 2);

    LOAD_HI(hin + i * HPS);
    (void)sqi;
    float ci[GH];
#pragma unroll
    for (int c = 0; c < GH; ++c) {
        float s = sb1[c];
#pragma unroll
        for (int d = 0; d < GH; ++d) s = fmaf(hi[d], sW1[d*GH+c], s);
        ci[c] = s;
    }
    float acc[GH];
#pragma unroll
    for (int c = 0; c < GH; ++c) acc[c] = 0.f;

    const int4 jj = *(const int4*)(idx + i*GK + t4*4);
    const int js[4] = { jj.x, jj.y, jj.z, jj.w };
#pragma unroll
    for (int nn = 0; nn < 4; ++nn) {
        const int j = js[nn];
        float dj[GH];
        {
            const float* hv = hin + j * HPS;
            float4 A = *(const float4*)(hv + 0);
            float4 B = *(const float4*)(hv + 4);
            float4 C = *(const float4*)(hv + 8);
            float4 D = *(const float4*)(hv + 12);
            dj[0]=A.x-hi[0]; dj[1]=A.y-hi[1]; dj[2]=A.z-hi[2]; dj[3]=A.w-hi[3];
            dj[4]=B.x-hi[4]; dj[5]=B.y-hi[5]; dj[6]=B.z-hi[6]; dj[7]=B.w-hi[7];
            dj[8]=C.x-hi[8]; dj[9]=C.y-hi[9]; dj[10]=C.z-hi[10]; dj[11]=C.w-hi[11];
            dj[12]=D.x-hi[12]; dj[13]=D.y-hi[13]; dj[14]=D.z-hi[14]; dj[15]=D.w-hi[15];
        }
        float msg[GH];
#pragma unroll
        for (int c = 0; c < GH; ++c) {
            float s = ci[c];
#pragma unroll
            for (int d = 0; d < GH; ++d) s = fmaf(dj[d], sW1[(GH+d)*GH+c], s);
            msg[c] = fmaxf(s, 0.f);
        }
#pragma unroll
        for (int c2 = 0; c2 < GH; ++c2) {
            float s = acc[c2];
#pragma unroll
            for (int c = 0; c < GH; ++c) s = fmaf(msg[c], sW2[c*GH+c2], s);
            acc[c2] = s;
        }
    }
#pragma unroll
    for (int c = 0; c < GH; ++c) {
        acc[c] += __shfl_xor(acc[c], 1);
        acc[c] += __shfl_xor(acc[c], 2);
    }
    if (t4 == 0) {
        float* orow = hout + i * HPS;
        float sq = 0.f;
#pragma unroll
        for (int c = 0; c < GH; ++c) {
            float v = acc[c] * (1.f/16.f) + sb2[c];
            orow[c] = v;
            sq = fmaf(v, v, sq);
        }
        orow[16] = sq;
    }
}

// ---------------------------------------------------------------------------
__global__ __launch_bounds__(256) void out_kernel(
    const float* __restrict__ hbase, const float* __restrict__ W,
    const float* __restrict__ b, void* __restrict__ out,
    const int* __restrict__ flag)
{
    int i = blockIdx.x * 256 + threadIdx.x;
    float a0 = b[0], a1 = b[1], a2 = b[2];
#pragma unroll
    for (int l = 0; l < GL; ++l) {
        const float* hp = hbase + l * GN * HPS + i * HPS;
#pragma unroll
        for (int c = 0; c < GH; ++c) {
            const float v = hp[c];
            const float* wr = W + (l * GH + c) * 3;
            a0 = fmaf(v, wr[0], a0);
            a1 = fmaf(v, wr[1], a1);
            a2 = fmaf(v, wr[2], a2);
        }
    }
    if (*flag) {
        __hip_bfloat16* o = (__hip_bfloat16*)out;
        o[i*3+0] = __float2bfloat16(a0);
        o[i*3+1] = __float2bfloat16(a1);
        o[i*3+2] = __float2bfloat16(a2);
    } else {
        float* o = (float*)out;
        o[i*3+0] = a0; o[i*3+1] = a1; o[i*3+2] = a2;
    }
}

// ---------------------------------------------------------------------------
extern "C" void kernel_launch(void* const* d_in, const int* in_sizes, int n_in,
                              void* d_out, int out_size, void* d_ws, size_t ws_size,
                              hipStream_t stream)
{
    float* wsf  = (float*)d_ws;
    int* idxb   = (int*)(wsf + OFF_IDX);
    int* flagsb = (int*)(wsf + OFF_FLAGS);
    int* dflag  = (int*)(wsf + OFF_DFLAG);

    detect_kernel<<<1, 64, 0, stream>>>((const unsigned short*)d_in[0], dflag);

    const int segoff[9] = {OFF_XF, OFF_EMBW, OFF_EMBB, OFF_W1, OFF_B1,
                           OFF_W2, OFF_B2, OFF_OW, OFF_OB};
    const int segn[9]   = {GN*3, 3*GH, GH, GL*2*GH*GH, GL*GH,
                           GL*GH*GH, GL*GH, GL*GH*3, 3};
    for (int s = 0; s < 9; ++s)
        convert_kernel<<<(segn[s] + 255)/256, 256, 0, stream>>>(
            d_in[s], wsf + segoff[s], segn[s], dflag);

    embed_kernel<<<GN/256, 256, 0, stream>>>(
        wsf + OFF_XF, wsf + OFF_EMBW, wsf + OFF_EMBB, wsf + OFF_H);

    for (int l = 0; l < GL; ++l) {
        const float* hin = wsf + OFF_H + l*GN*HPS;
        float* hout      = wsf + OFF_H + (l+1)*GN*HPS;
        knn11_kernel<<<GN/RPB, TPB, 0, stream>>>(hin, idxb, flagsb);
        rescue_kernel<<<GN/RPB, 1024, 0, stream>>>(hin, flagsb, idxb);
        edgeconv_kernel<<<GN/64, 256, 0, stream>>>(hin, idxb,
            wsf + OFF_W1 + l*2*GH*GH, wsf + OFF_B1 + l*GH,
            wsf + OFF_W2 + l*GH*GH,  wsf + OFF_B2 + l*GH, hout);
    }

    out_kernel<<<GN/256, 256, 0, stream>>>(
        wsf + OFF_H + GN*HPS, wsf + OFF_OW, wsf + OFF_OB, d_out, dflag);
}